// Round 1
// baseline (576.712 us; speedup 1.0000x reference)
//
#include <hip/hip_runtime.h>
#include <hip/hip_bf16.h>
#include <math.h>

#define K_CODES 512
#define D_FULL 512
#define SUB_D 128
#define N_D 4
#define B_SZ 16
#define T_SZ 2048
#define N_TOK (B_SZ * T_SZ)   // 32768
#define TILE 32               // tokens per block
#define QS_STRIDE 33          // f32 elems per Qs row (32 + 1 pad)

typedef __attribute__((ext_vector_type(8))) short short8;
typedef __attribute__((ext_vector_type(16))) float f32x16;

__device__ __forceinline__ unsigned short f2bf(float f) {
    __hip_bfloat16 h = __float2bfloat16(f);   // RNE
    return *reinterpret_cast<unsigned short*>(&h);
}
__device__ __forceinline__ float bf2f(unsigned short u) {
    unsigned int v = ((unsigned int)u) << 16;
    return __uint_as_float(v);
}

// LDS map (40960 B total -> exactly 4 blocks/CU at 160 KiB LDS):
//   enc  [0, 32768): bf16 32 x 512, XOR-swizzled (col ^= (r&7)<<3, 8-elem granule).
//        Aliased in time by: per-wave gumbel bounce scratch + Sred pads (pre enc-store),
//        and by Qs (f32 128x33) after phase D.
//   xs   [32768, 40960): bf16 32 x 128, XOR-swizzled (d ^= (t&7)<<3).
//        Read-only after B1; never clobbered (scratch lives in enc region now),
//        so afrag can stream from LDS inside the MFMA loop (no preload, no B2).
// Per-wave scratch slice: 544 f32 (2176 B): [0,512) bounce rows, [512,544) Sred pad.
#define XS_OFF  32768
#define SMEM_SZ 40960

__device__ __forceinline__ int enc_idx(int r, int c) { return r * 512 + (c ^ ((r & 7) << 3)); }
__device__ __forceinline__ int xs_idx(int t, int d)  { return t * 128 + (d ^ ((t & 7) << 3)); }

__global__ __launch_bounds__(256, 4) void vq_kernel(
    const float* __restrict__ x,
    const unsigned short* __restrict__ Wbf,    // [g][512][128] bf16
    const unsigned short* __restrict__ WTbf,   // [g][128][512] bf16
    const float* __restrict__ csqr,            // [g][512]
    const float* __restrict__ gum,
    float* __restrict__ out,
    float* __restrict__ wsum, int Rmask)
{
    __shared__ __align__(16) char smem[SMEM_SZ];
    unsigned short* enc = (unsigned short*)smem;
    unsigned short* xs  = (unsigned short*)(smem + XS_OFF);
    float* Sp   = (float*)smem;                // scratch view of enc region
    float* Qs   = (float*)smem;                // aliases enc (barrier-protected)

    const int tid = threadIdx.x;
    const int g = blockIdx.y;
    const int n0 = blockIdx.x * TILE;
    const int b = n0 / T_SZ;
    const int t0 = n0 % T_SZ;
    const int wave = tid >> 6, lane = tid & 63;
    const int half = lane >> 5, l31 = lane & 31;

    // ---- phase A: x tile -> LDS bf16, [token][d], swizzled ----
    const float* xbase = x + ((size_t)b * D_FULL + g * SUB_D) * T_SZ + t0;
    #pragma unroll
    for (int it = 0; it < 4; ++it) {
        int idx = tid + it * 256;          // 0..1023
        int tq = idx & 7, d = idx >> 3;
        float4 v = *(const float4*)(xbase + (size_t)d * T_SZ + tq * 4);
        int t = tq * 4;
        xs[xs_idx(t + 0, d)] = f2bf(v.x);
        xs[xs_idx(t + 1, d)] = f2bf(v.y);
        xs[xs_idx(t + 2, d)] = f2bf(v.z);
        xs[xs_idx(t + 3, d)] = f2bf(v.w);
    }
    __syncthreads();                       // B1: xs ready

    // csq loaded EARLY (before W/gumbel loads) so its vmcnt wait never drains them
    float csq[4];
    #pragma unroll
    for (int ct = 0; ct < 4; ++ct)
        csq[ct] = csqr[g * K_CODES + wave * 128 + ct * 32 + l31];

    // ---- phase B: cross = x . W^T via MFMA 32x32x16, afrag streamed from LDS ----
    const unsigned short* Wg = Wbf + (size_t)g * K_CODES * SUB_D;
    f32x16 acc[4];
    #pragma unroll
    for (int ct = 0; ct < 4; ++ct)
        #pragma unroll
        for (int i = 0; i < 16; ++i) acc[ct][i] = 0.f;

    #pragma unroll
    for (int s = 0; s < 8; ++s) {
        short8 af = *(const short8*)(xs + xs_idx(l31, s * 16 + half * 8));
        #pragma unroll
        for (int ct = 0; ct < 4; ++ct) {
            short8 bfrag = *(const short8*)(Wg + (size_t)(wave * 128 + ct * 32 + l31) * SUB_D
                                            + s * 16 + half * 8);
            acc[ct] = __builtin_amdgcn_mfma_f32_32x32x16_bf16(af, bfrag, acc[ct], 0, 0, 0);
        }
    }

    // keep gumbel loads AFTER all W-fragment loads (in-order vmcnt: waiting on a
    // load also waits everything older -> gumbels must be the newest)
    __builtin_amdgcn_sched_barrier(0);

    // ---- gumbel slice for this wave: 32 tokens x 128 codes, 16x dwordx4 ----
    const float* gw = gum + ((size_t)g * N_TOK + n0) * K_CODES + wave * 128;
    float4 f[16];
    #pragma unroll
    for (int k = 0; k < 16; ++k)           // chunk k: rows {2k, 2k+1}, cc = 4*l31
        f[k] = *(const float4*)(gw + (size_t)(2 * k + half) * K_CODES + 4 * l31);

    // ---- bounce through per-wave scratch (enc region) + fused exp/ssum ----
    float* Sw = Sp + wave * 544;           // 2176 B per wave inside enc region
    float ssum[16];
    #pragma unroll
    for (int i = 0; i < 16; ++i) ssum[i] = 0.f;

    #pragma unroll
    for (int j = 0; j < 8; ++j) {          // round j: tokens 4j..4j+3
        *(float4*)(Sw + half * 128 + 4 * l31)       = f[2 * j];      // rows 4j,4j+1
        *(float4*)(Sw + 256 + half * 128 + 4 * l31) = f[2 * j + 1];  // rows 4j+2,4j+3
        int hj = j & 1;
        if (half == hj) {                  // this half's tokens live in rows 4j+4h..+3
            int q = (j - hj) >> 1;         // = i>>2
            #pragma unroll
            for (int ct = 0; ct < 4; ++ct)
                #pragma unroll
                for (int m = 0; m < 4; ++m) {
                    float gv = Sw[m * 128 + ct * 32 + l31];
                    int i = q * 4 + m;
                    float e = __expf(acc[ct][i] - 0.5f * csq[ct] + 0.5f * gv);
                    acc[ct][i] = e;        // no max-subtract: logits bounded ~[-2, 9]
                    ssum[i] += e;
                }
        }
    }

    // ---- softmax denominator: 32-lane butterfly + cross-wave via scratch pads ----
    #pragma unroll
    for (int i = 0; i < 16; ++i) {
        float s = ssum[i];
        s += __shfl_xor(s, 1);  s += __shfl_xor(s, 2);
        s += __shfl_xor(s, 4);  s += __shfl_xor(s, 8);
        s += __shfl_xor(s, 16);
        ssum[i] = s;
    }
    if (l31 == 0) {
        #pragma unroll
        for (int i = 0; i < 16; ++i)
            Sw[512 + (i & 3) + 8 * (i >> 2) + 4 * half] = ssum[i];
    }
    __syncthreads();                       // B3: all pads written

    float rinv[16];
    #pragma unroll
    for (int i = 0; i < 16; ++i) {
        int r = (i & 3) + 8 * (i >> 2) + 4 * half;
        // 4 broadcast LDS reads (wave-uniform addr per half) from the 4 wave pads
        float s = Sp[512 + r] + Sp[544 + 512 + r] + Sp[1088 + 512 + r] + Sp[1632 + 512 + r];
        rinv[i] = 1.f / s;
    }
    __syncthreads();                       // B3.5: pads consumed, enc region reusable

    // ---- enc -> LDS bf16 (swizzled) + avg_probs atomics ----
    float* wrep = wsum + (size_t)(blockIdx.x & Rmask) * (N_D * K_CODES) + g * K_CODES;
    #pragma unroll
    for (int ct = 0; ct < 4; ++ct) {
        float s = 0.f;
        #pragma unroll
        for (int i = 0; i < 16; ++i) {
            int r = (i & 3) + 8 * (i >> 2) + 4 * half;
            float p = acc[ct][i] * rinv[i];
            enc[enc_idx(r, wave * 128 + ct * 32 + l31)] = f2bf(p);
            s += p;
        }
        s += __shfl_xor(s, 32);
        if (half == 0) atomicAdd(wrep + wave * 128 + ct * 32 + l31, s);
    }
    __syncthreads();                       // B4: enc ready

    // ---- phase D: quant = enc . W via MFMA, wave owns 32 out-dims ----
    const unsigned short* Btrow = WTbf + (size_t)g * SUB_D * K_CODES
                                + (size_t)(wave * 32 + l31) * K_CODES + half * 8;
    f32x16 q0, q1;
    #pragma unroll
    for (int i = 0; i < 16; ++i) { q0[i] = 0.f; q1[i] = 0.f; }
    #pragma unroll
    for (int s = 0; s < 32; s += 2) {
        short8 a0 = *(const short8*)(enc + enc_idx(l31, (s + 0) * 16 + half * 8));
        short8 b0 = *(const short8*)(Btrow + (s + 0) * 16);
        short8 a1 = *(const short8*)(enc + enc_idx(l31, (s + 1) * 16 + half * 8));
        short8 b1 = *(const short8*)(Btrow + (s + 1) * 16);
        q0 = __builtin_amdgcn_mfma_f32_32x32x16_bf16(a0, b0, q0, 0, 0, 0);
        q1 = __builtin_amdgcn_mfma_f32_32x32x16_bf16(a1, b1, q1, 0, 0, 0);
    }
    __syncthreads();                       // B5: enc reads done, Qs may overwrite

    #pragma unroll
    for (int i = 0; i < 16; ++i) {
        int r = (i & 3) + 8 * (i >> 2) + 4 * half;
        Qs[(wave * 32 + l31) * QS_STRIDE + r] = q0[i] + q1[i];
    }
    __syncthreads();                       // B6

    // ---- write out [b, g*128+j, t0+t], 128B segments ----
    float* obase = out + ((size_t)b * D_FULL + g * SUB_D) * T_SZ + t0;
    #pragma unroll
    for (int it = 0; it < 4; ++it) {
        int idx = tid + it * 256;
        int t4 = (idx & 7) * 4, j = idx >> 3;
        float4 v;
        v.x = Qs[j * QS_STRIDE + t4 + 0];
        v.y = Qs[j * QS_STRIDE + t4 + 1];
        v.z = Qs[j * QS_STRIDE + t4 + 2];
        v.w = Qs[j * QS_STRIDE + t4 + 3];
        *(float4*)(obase + (size_t)j * T_SZ + t4) = v;
    }
}

__global__ __launch_bounds__(256) void prep_kernel(
    const float* __restrict__ W1, const float* __restrict__ W2,
    const float* __restrict__ W3, const float* __restrict__ W4,
    unsigned short* __restrict__ Wbf, unsigned short* __restrict__ WTbf,
    float* __restrict__ csqr)
{
    const int g = blockIdx.x, kc = blockIdx.y;   // 64 codes per block
    const float* Wg = (g == 0) ? W1 : ((g == 1) ? W2 : ((g == 2) ? W3 : W4));
    const int tid = threadIdx.x;
    const int k0 = kc * 64;
    __shared__ float tile[64][129];              // bf16-rounded values

    #pragma unroll
    for (int it = 0; it < 8; ++it) {
        int idx = tid + it * 256;                // 2048 float4 total
        int k = idx >> 5, d4 = (idx & 31) * 4;
        float4 v = *(const float4*)(Wg + (size_t)(k0 + k) * SUB_D + d4);
        unsigned short p0 = f2bf(v.x), p1 = f2bf(v.y), p2 = f2bf(v.z), p3 = f2bf(v.w);
        tile[k][d4 + 0] = bf2f(p0); tile[k][d4 + 1] = bf2f(p1);
        tile[k][d4 + 2] = bf2f(p2); tile[k][d4 + 3] = bf2f(p3);
        ushort4 pk; pk.x = p0; pk.y = p1; pk.z = p2; pk.w = p3;
        *(ushort4*)(Wbf + (size_t)g * K_CODES * SUB_D + (size_t)(k0 + k) * SUB_D + d4) = pk;
    }
    __syncthreads();

    #pragma unroll
    for (int it = 0; it < 4; ++it) {
        int idx = tid + it * 256;                // 1024 short8 chunks
        int d = idx >> 3, c8 = (idx & 7) * 8;
        union { unsigned short u[8]; short8 v; } pk;
        #pragma unroll
        for (int j = 0; j < 8; ++j) pk.u[j] = f2bf(tile[c8 + j][d]);
        *(short8*)(WTbf + (size_t)g * SUB_D * K_CODES + (size_t)d * K_CODES + k0 + c8) = pk.v;
    }

    if (tid < 64) {
        float ssq = 0.f;
        #pragma unroll 16
        for (int d = 0; d < SUB_D; ++d) { float wv = tile[tid][d]; ssq += wv * wv; }
        csqr[g * K_CODES + k0 + tid] = ssq;
    }
}

__global__ __launch_bounds__(256) void perp_kernel(
    const float* __restrict__ wsum, int R, float* __restrict__ out)
{
    const int tid = threadIdx.x;
    const int lane = tid & 63, wave = tid >> 6;
    __shared__ float red[N_D][4];
    float part[N_D];
    #pragma unroll
    for (int g = 0; g < N_D; ++g) part[g] = 0.f;

    for (int g = 0; g < N_D; ++g) {
        for (int kk = tid; kk < K_CODES; kk += 256) {
            float s = 0.f;
            for (int r = 0; r < R; ++r) s += wsum[(size_t)r * (N_D * K_CODES) + g * K_CODES + kk];
            float p = s * (1.0f / N_TOK);
            part[g] += p * logf(p + 1e-10f);
        }
    }
    #pragma unroll
    for (int g = 0; g < N_D; ++g) {
        float v = part[g];
        #pragma unroll
        for (int off = 32; off; off >>= 1) v += __shfl_xor(v, off);
        if (lane == 0) red[g][wave] = v;
    }
    __syncthreads();
    if (tid == 0) {
        float perp = 0.f;
        #pragma unroll
        for (int g = 0; g < N_D; ++g) {
            float e = red[g][0] + red[g][1] + red[g][2] + red[g][3];
            perp += __expf(-e);
        }
        out[(size_t)B_SZ * D_FULL * T_SZ] = perp;
    }
}

extern "C" void kernel_launch(void* const* d_in, const int* in_sizes, int n_in,
                              void* d_out, int out_size, void* d_ws, size_t ws_size,
                              hipStream_t stream) {
    const float* x   = (const float*)d_in[0];
    const float* W1  = (const float*)d_in[1];
    const float* W2  = (const float*)d_in[2];
    const float* W3  = (const float*)d_in[3];
    const float* W4  = (const float*)d_in[4];
    const float* gum = (const float*)d_in[5];
    float* out = (float*)d_out;

    // ws layout: Wbf (512KB) | WTbf (512KB) | csqr (8KB) | wsum (R * 8KB)
    unsigned short* Wbf  = (unsigned short*)d_ws;
    unsigned short* WTbf = Wbf + (size_t)N_D * K_CODES * SUB_D;
    float* csqr = (float*)(WTbf + (size_t)N_D * K_CODES * SUB_D);
    float* wsum = csqr + N_D * K_CODES;

    size_t fixed = (size_t)N_D * K_CODES * SUB_D * 2 * 2 + (size_t)N_D * K_CODES * 4;
    size_t rem = (ws_size > fixed) ? (ws_size - fixed) : 0;
    int maxR = (int)(rem / ((size_t)N_D * K_CODES * 4));
    int R = 1;
    while (R * 2 <= maxR && R < 16) R *= 2;

    hipMemsetAsync(wsum, 0, (size_t)R * N_D * K_CODES * sizeof(float), stream);
    prep_kernel<<<dim3(4, 8), 256, 0, stream>>>(W1, W2, W3, W4, Wbf, WTbf, csqr);
    vq_kernel<<<dim3(N_TOK / TILE, N_D), 256, 0, stream>>>(x, Wbf, WTbf, csqr, gum, out, wsum, R - 1);
    perp_kernel<<<1, 256, 0, stream>>>(wsum, R, out);
}

// Round 2
// 572.513 us; speedup vs baseline: 1.0073x; 1.0073x over previous
//
#include <hip/hip_runtime.h>
#include <hip/hip_bf16.h>
#include <math.h>
#include <stdint.h>

#define K_CODES 512
#define D_FULL 512
#define SUB_D 128
#define N_D 4
#define B_SZ 16
#define T_SZ 2048
#define N_TOK (B_SZ * T_SZ)   // 32768
#define TILE 32               // tokens per block
#define QS_STRIDE 33          // f32 elems per Qs row (32 + 1 pad)

typedef __attribute__((ext_vector_type(8))) short short8;
typedef __attribute__((ext_vector_type(16))) float f32x16;

__device__ __forceinline__ unsigned short f2bf(float f) {
    __hip_bfloat16 h = __float2bfloat16(f);   // RNE
    return *reinterpret_cast<unsigned short*>(&h);
}
__device__ __forceinline__ float bf2f(unsigned short u) {
    unsigned int v = ((unsigned int)u) << 16;
    return __uint_as_float(v);
}

// HBM -> LDS direct DMA, 16B per lane, zero VGPR result footprint.
// LDS dest = (wave-uniform base) + laneid*16B; global src is per-lane.
// AS casts via uintptr (CK pattern): LDS offset == low 32 bits of generic ptr.
__device__ __forceinline__ void gld_lds16(const float* g, float* l) {
    auto gp = reinterpret_cast<const __attribute__((address_space(1))) unsigned int*>(
        reinterpret_cast<uintptr_t>(g));
    auto lp = reinterpret_cast<__attribute__((address_space(3))) unsigned int*>(
        static_cast<unsigned int>(reinterpret_cast<uintptr_t>(l)));
    __builtin_amdgcn_global_load_lds(gp, lp, 16, 0, 0);
}

// LDS map (40960 B total -> 4 blocks/CU at 160 KiB LDS):
//   enc  [0, 32768): bf16 32 x 512, XOR-swizzled (col ^= (r&7)<<3, 8-elem granule).
//        Aliased in time by: per-wave gumbel DMA ring (3 x 2KB per wave = 24 KB)
//        + Sred pads at float [6144, 6272), both dead before enc stores (barriers),
//        and by Qs (f32 128x33) after phase D.
//   xs   [32768, 40960): bf16 32 x 128, XOR-swizzled (d ^= (t&7)<<3). Read-only after B1.
#define XS_OFF  32768
#define SMEM_SZ 40960
#define PAD_F   6144          // float index of Sred pads inside enc region

__device__ __forceinline__ int enc_idx(int r, int c) { return r * 512 + (c ^ ((r & 7) << 3)); }
__device__ __forceinline__ int xs_idx(int t, int d)  { return t * 128 + (d ^ ((t & 7) << 3)); }

__global__ __launch_bounds__(256, 4) void vq_kernel(
    const float* __restrict__ x,
    const unsigned short* __restrict__ Wbf,    // [g][512][128] bf16
    const unsigned short* __restrict__ WTbf,   // [g][128][512] bf16
    const float* __restrict__ csqr,            // [g][512]
    const float* __restrict__ gum,
    float* __restrict__ out,
    float* __restrict__ wsum, int Rmask)
{
    __shared__ __align__(16) char smem[SMEM_SZ];
    unsigned short* enc = (unsigned short*)smem;
    unsigned short* xs  = (unsigned short*)(smem + XS_OFF);
    float* Sp   = (float*)smem;                // scratch view of enc region
    float* Qs   = (float*)smem;                // aliases enc (barrier-protected)

    const int tid = threadIdx.x;
    const int g = blockIdx.y;
    const int n0 = blockIdx.x * TILE;
    const int b = n0 / T_SZ;
    const int t0 = n0 % T_SZ;
    const int wave = tid >> 6, lane = tid & 63;
    const int half = lane >> 5, l31 = lane & 31;

    // ---- phase A: x tile -> LDS bf16, [token][d], swizzled ----
    const float* xbase = x + ((size_t)b * D_FULL + g * SUB_D) * T_SZ + t0;
    #pragma unroll
    for (int it = 0; it < 4; ++it) {
        int idx = tid + it * 256;          // 0..1023
        int tq = idx & 7, d = idx >> 3;
        float4 v = *(const float4*)(xbase + (size_t)d * T_SZ + tq * 4);
        int t = tq * 4;
        xs[xs_idx(t + 0, d)] = f2bf(v.x);
        xs[xs_idx(t + 1, d)] = f2bf(v.y);
        xs[xs_idx(t + 2, d)] = f2bf(v.z);
        xs[xs_idx(t + 3, d)] = f2bf(v.w);
    }
    __syncthreads();                       // B1: xs ready

    // csq loaded EARLY so later waits on it never drain the DMA stream
    float csq[4];
    #pragma unroll
    for (int ct = 0; ct < 4; ++ct)
        csq[ct] = csqr[g * K_CODES + wave * 128 + ct * 32 + l31];

    // ---- gumbel DMA ring: per-wave 3 buffers x 512 f32 in enc region ----
    // Round j covers tokens 4j..4j+3 x 128 codes (2 KB). Lane (half,l31):
    // inst0 row 4j+half, inst1 row 4j+2+half, codes 4*l31..+3 -> LDS layout
    // identical to the old bounce layout: buf[m*128 + 4*l31 + c].
    const float* gw = gum + ((size_t)g * N_TOK + n0) * K_CODES + wave * 128;
    float* Sw = Sp + wave * 1536;          // 3 x 512 floats per wave

    #define ISSUE_ROUND(j_) do { \
        float* dst_ = Sw + ((j_) % 3) * 512; \
        gld_lds16(gw + (size_t)(4 * (j_) + half) * K_CODES + 4 * l31, dst_); \
        gld_lds16(gw + (size_t)(4 * (j_) + 2 + half) * K_CODES + 4 * l31, dst_ + 256); \
    } while (0)

    // prologue: 3 rounds in flight; their latency hides under phase B MFMA
    ISSUE_ROUND(0); ISSUE_ROUND(1); ISSUE_ROUND(2);

    // ---- phase B: cross = x . W^T via MFMA 32x32x16, afrag streamed from LDS ----
    const unsigned short* Wg = Wbf + (size_t)g * K_CODES * SUB_D;
    f32x16 acc[4];
    #pragma unroll
    for (int ct = 0; ct < 4; ++ct)
        #pragma unroll
        for (int i = 0; i < 16; ++i) acc[ct][i] = 0.f;

    #pragma unroll
    for (int s = 0; s < 8; ++s) {
        short8 af = *(const short8*)(xs + xs_idx(l31, s * 16 + half * 8));
        #pragma unroll
        for (int ct = 0; ct < 4; ++ct) {
            short8 bfrag = *(const short8*)(Wg + (size_t)(wave * 128 + ct * 32 + l31) * SUB_D
                                            + s * 16 + half * 8);
            acc[ct] = __builtin_amdgcn_mfma_f32_32x32x16_bf16(af, bfrag, acc[ct], 0, 0, 0);
        }
    }

    // ---- bounce: consume DMA'd gumbels from LDS, fused exp/ssum ----
    float ssum[16];
    #pragma unroll
    for (int i = 0; i < 16; ++i) ssum[i] = 0.f;

    #pragma unroll
    for (int j = 0; j < 8; ++j) {
        // counted waits (T4): round j's 2 loads retired; keep newer rounds in flight
        if (j < 6)      asm volatile("s_waitcnt vmcnt(4)" ::: "memory");
        else if (j == 6) asm volatile("s_waitcnt vmcnt(2)" ::: "memory");
        else             asm volatile("s_waitcnt vmcnt(0)" ::: "memory");
        __builtin_amdgcn_sched_barrier(0);

        int hj = j & 1;
        if (half == hj) {                  // tokens 4j..4j+3 live in this half's acc rows
            const float* Sb = Sw + (j % 3) * 512;
            int q = j >> 1;
            #pragma unroll
            for (int ct = 0; ct < 4; ++ct)
                #pragma unroll
                for (int m = 0; m < 4; ++m) {
                    float gv = Sb[m * 128 + ct * 32 + l31];
                    int i = q * 4 + m;
                    float e = __expf(acc[ct][i] - 0.5f * csq[ct] + 0.5f * gv);
                    acc[ct][i] = e;        // no max-subtract: logits bounded ~[-2, 9]
                    ssum[i] += e;
                }
        }
        if (j < 5) ISSUE_ROUND(j + 3);     // reuse buffer j%3 after its reads
    }
    #undef ISSUE_ROUND

    // ---- softmax denominator: 32-lane butterfly + cross-wave via pads ----
    #pragma unroll
    for (int i = 0; i < 16; ++i) {
        float s = ssum[i];
        s += __shfl_xor(s, 1);  s += __shfl_xor(s, 2);
        s += __shfl_xor(s, 4);  s += __shfl_xor(s, 8);
        s += __shfl_xor(s, 16);
        ssum[i] = s;
    }
    if (l31 == 0) {
        #pragma unroll
        for (int i = 0; i < 16; ++i)
            Sp[PAD_F + wave * 32 + (i & 3) + 8 * (i >> 2) + 4 * half] = ssum[i];
    }
    __syncthreads();                       // B3: all pads written

    float rinv[16];
    #pragma unroll
    for (int i = 0; i < 16; ++i) {
        int r = (i & 3) + 8 * (i >> 2) + 4 * half;
        float s = Sp[PAD_F + r] + Sp[PAD_F + 32 + r] + Sp[PAD_F + 64 + r] + Sp[PAD_F + 96 + r];
        rinv[i] = 1.f / s;
    }
    __syncthreads();                       // B3.5: pads consumed, enc region reusable

    // ---- enc -> LDS bf16 (swizzled) + avg_probs atomics ----
    float* wrep = wsum + (size_t)(blockIdx.x & Rmask) * (N_D * K_CODES) + g * K_CODES;
    #pragma unroll
    for (int ct = 0; ct < 4; ++ct) {
        float s = 0.f;
        #pragma unroll
        for (int i = 0; i < 16; ++i) {
            int r = (i & 3) + 8 * (i >> 2) + 4 * half;
            float p = acc[ct][i] * rinv[i];
            enc[enc_idx(r, wave * 128 + ct * 32 + l31)] = f2bf(p);
            s += p;
        }
        s += __shfl_xor(s, 32);
        if (half == 0) atomicAdd(wrep + wave * 128 + ct * 32 + l31, s);
    }
    __syncthreads();                       // B4: enc ready

    // ---- phase D: quant = enc . W via MFMA, wave owns 32 out-dims ----
    const unsigned short* Btrow = WTbf + (size_t)g * SUB_D * K_CODES
                                + (size_t)(wave * 32 + l31) * K_CODES + half * 8;
    f32x16 q0, q1;
    #pragma unroll
    for (int i = 0; i < 16; ++i) { q0[i] = 0.f; q1[i] = 0.f; }
    #pragma unroll
    for (int s = 0; s < 32; s += 2) {
        short8 a0 = *(const short8*)(enc + enc_idx(l31, (s + 0) * 16 + half * 8));
        short8 b0 = *(const short8*)(Btrow + (s + 0) * 16);
        short8 a1 = *(const short8*)(enc + enc_idx(l31, (s + 1) * 16 + half * 8));
        short8 b1 = *(const short8*)(Btrow + (s + 1) * 16);
        q0 = __builtin_amdgcn_mfma_f32_32x32x16_bf16(a0, b0, q0, 0, 0, 0);
        q1 = __builtin_amdgcn_mfma_f32_32x32x16_bf16(a1, b1, q1, 0, 0, 0);
    }
    __syncthreads();                       // B5: enc reads done, Qs may overwrite

    #pragma unroll
    for (int i = 0; i < 16; ++i) {
        int r = (i & 3) + 8 * (i >> 2) + 4 * half;
        Qs[(wave * 32 + l31) * QS_STRIDE + r] = q0[i] + q1[i];
    }
    __syncthreads();                       // B6

    // ---- write out [b, g*128+j, t0+t], 128B segments ----
    float* obase = out + ((size_t)b * D_FULL + g * SUB_D) * T_SZ + t0;
    #pragma unroll
    for (int it = 0; it < 4; ++it) {
        int idx = tid + it * 256;
        int t4 = (idx & 7) * 4, j = idx >> 3;
        float4 v;
        v.x = Qs[j * QS_STRIDE + t4 + 0];
        v.y = Qs[j * QS_STRIDE + t4 + 1];
        v.z = Qs[j * QS_STRIDE + t4 + 2];
        v.w = Qs[j * QS_STRIDE + t4 + 3];
        *(float4*)(obase + (size_t)j * T_SZ + t4) = v;
    }
}

__global__ __launch_bounds__(256) void prep_kernel(
    const float* __restrict__ W1, const float* __restrict__ W2,
    const float* __restrict__ W3, const float* __restrict__ W4,
    unsigned short* __restrict__ Wbf, unsigned short* __restrict__ WTbf,
    float* __restrict__ csqr)
{
    const int g = blockIdx.x, kc = blockIdx.y;   // 64 codes per block
    const float* Wg = (g == 0) ? W1 : ((g == 1) ? W2 : ((g == 2) ? W3 : W4));
    const int tid = threadIdx.x;
    const int k0 = kc * 64;
    __shared__ float tile[64][129];              // bf16-rounded values

    #pragma unroll
    for (int it = 0; it < 8; ++it) {
        int idx = tid + it * 256;                // 2048 float4 total
        int k = idx >> 5, d4 = (idx & 31) * 4;
        float4 v = *(const float4*)(Wg + (size_t)(k0 + k) * SUB_D + d4);
        unsigned short p0 = f2bf(v.x), p1 = f2bf(v.y), p2 = f2bf(v.z), p3 = f2bf(v.w);
        tile[k][d4 + 0] = bf2f(p0); tile[k][d4 + 1] = bf2f(p1);
        tile[k][d4 + 2] = bf2f(p2); tile[k][d4 + 3] = bf2f(p3);
        ushort4 pk; pk.x = p0; pk.y = p1; pk.z = p2; pk.w = p3;
        *(ushort4*)(Wbf + (size_t)g * K_CODES * SUB_D + (size_t)(k0 + k) * SUB_D + d4) = pk;
    }
    __syncthreads();

    #pragma unroll
    for (int it = 0; it < 4; ++it) {
        int idx = tid + it * 256;                // 1024 short8 chunks
        int d = idx >> 3, c8 = (idx & 7) * 8;
        union { unsigned short u[8]; short8 v; } pk;
        #pragma unroll
        for (int j = 0; j < 8; ++j) pk.u[j] = f2bf(tile[c8 + j][d]);
        *(short8*)(WTbf + (size_t)g * SUB_D * K_CODES + (size_t)d * K_CODES + k0 + c8) = pk.v;
    }

    if (tid < 64) {
        float ssq = 0.f;
        #pragma unroll 16
        for (int d = 0; d < SUB_D; ++d) { float wv = tile[tid][d]; ssq += wv * wv; }
        csqr[g * K_CODES + k0 + tid] = ssq;
    }
}

__global__ __launch_bounds__(256) void perp_kernel(
    const float* __restrict__ wsum, int R, float* __restrict__ out)
{
    const int tid = threadIdx.x;
    const int lane = tid & 63, wave = tid >> 6;
    __shared__ float red[N_D][4];
    float part[N_D];
    #pragma unroll
    for (int g = 0; g < N_D; ++g) part[g] = 0.f;

    for (int g = 0; g < N_D; ++g) {
        for (int kk = tid; kk < K_CODES; kk += 256) {
            float s = 0.f;
            for (int r = 0; r < R; ++r) s += wsum[(size_t)r * (N_D * K_CODES) + g * K_CODES + kk];
            float p = s * (1.0f / N_TOK);
            part[g] += p * logf(p + 1e-10f);
        }
    }
    #pragma unroll
    for (int g = 0; g < N_D; ++g) {
        float v = part[g];
        #pragma unroll
        for (int off = 32; off; off >>= 1) v += __shfl_xor(v, off);
        if (lane == 0) red[g][wave] = v;
    }
    __syncthreads();
    if (tid == 0) {
        float perp = 0.f;
        #pragma unroll
        for (int g = 0; g < N_D; ++g) {
            float e = red[g][0] + red[g][1] + red[g][2] + red[g][3];
            perp += __expf(-e);
        }
        out[(size_t)B_SZ * D_FULL * T_SZ] = perp;
    }
}

extern "C" void kernel_launch(void* const* d_in, const int* in_sizes, int n_in,
                              void* d_out, int out_size, void* d_ws, size_t ws_size,
                              hipStream_t stream) {
    const float* x   = (const float*)d_in[0];
    const float* W1  = (const float*)d_in[1];
    const float* W2  = (const float*)d_in[2];
    const float* W3  = (const float*)d_in[3];
    const float* W4  = (const float*)d_in[4];
    const float* gum = (const float*)d_in[5];
    float* out = (float*)d_out;

    // ws layout: Wbf (512KB) | WTbf (512KB) | csqr (8KB) | wsum (R * 8KB)
    unsigned short* Wbf  = (unsigned short*)d_ws;
    unsigned short* WTbf = Wbf + (size_t)N_D * K_CODES * SUB_D;
    float* csqr = (float*)(WTbf + (size_t)N_D * K_CODES * SUB_D);
    float* wsum = csqr + N_D * K_CODES;

    size_t fixed = (size_t)N_D * K_CODES * SUB_D * 2 * 2 + (size_t)N_D * K_CODES * 4;
    size_t rem = (ws_size > fixed) ? (ws_size - fixed) : 0;
    int maxR = (int)(rem / ((size_t)N_D * K_CODES * 4));
    int R = 1;
    while (R * 2 <= maxR && R < 16) R *= 2;

    hipMemsetAsync(wsum, 0, (size_t)R * N_D * K_CODES * sizeof(float), stream);
    prep_kernel<<<dim3(4, 8), 256, 0, stream>>>(W1, W2, W3, W4, Wbf, WTbf, csqr);
    vq_kernel<<<dim3(N_TOK / TILE, N_D), 256, 0, stream>>>(x, Wbf, WTbf, csqr, gum, out, wsum, R - 1);
    perp_kernel<<<1, 256, 0, stream>>>(wsum, R, out);
}